// Round 4
// baseline (383.002 us; speedup 1.0000x reference)
//
#include <hip/hip_runtime.h>
#include <math.h>

#define B_ 2
#define N_ 2048
#define E_ 1024
#define H_ 16
#define D_ 64
#define NE_ (B_*H_*N_*D_) // 4194304 elements per tensor

typedef unsigned short US;
typedef _Float16 h16x8 __attribute__((ext_vector_type(8)));
typedef float f32x4 __attribute__((ext_vector_type(4)));
#define MFMA16F(a,b,c) __builtin_amdgcn_mfma_f32_16x16x32_f16(a,b,c,0,0,0)

union HU { _Float16 h; US u; };
__device__ __forceinline__ US f2h(float f){ HU x; x.h = (_Float16)f; return x.u; }

union U8 { US u[8]; uint4 v; };
union U4 { US u[4]; uint2 v; };

// async global->LDS, 16B per lane; LDS dest = wave-uniform base + lane*16
__device__ __forceinline__ void glds16(const US* g, US* l){
  __builtin_amdgcn_global_load_lds(
    (const __attribute__((address_space(1))) unsigned int*)(const void*)g,
    (__attribute__((address_space(3))) unsigned int*)(void*)l, 16, 0, 0);
}

// ---- converts: fp32 -> fp16 ----
__global__ __launch_bounds__(256) void conv_x(const float* __restrict__ x, US* __restrict__ hi)
{
  int i = (blockIdx.x*256 + threadIdx.x)*8;
  float f[8];
  *(float4*)&f[0] = *(const float4*)&x[i];
  *(float4*)&f[4] = *(const float4*)&x[i+4];
  U8 h;
  #pragma unroll
  for (int j=0;j<8;++j) h.u[j] = f2h(f[j]);
  *(uint4*)&hi[i] = h.v;
}

__global__ __launch_bounds__(256) void conv_w(const float* __restrict__ w0, const float* __restrict__ w1,
                                              const float* __restrict__ w2, const float* __restrict__ w3,
                                              US* __restrict__ d0, US* __restrict__ d1,
                                              US* __restrict__ d2, US* __restrict__ d3)
{
  const float* s; US* d;
  switch (blockIdx.y) {
    case 0: s=w0; d=d0; break;
    case 1: s=w1; d=d1; break;
    case 2: s=w2; d=d2; break;
    default: s=w3; d=d3; break;
  }
  int i = (blockIdx.x*256 + threadIdx.x)*8;
  float f[8];
  *(float4*)&f[0] = *(const float4*)&s[i];
  *(float4*)&f[4] = *(const float4*)&s[i+4];
  U8 h;
  #pragma unroll
  for (int j=0;j<8;++j) h.u[j] = f2h(f[j]);
  *(uint4*)&d[i] = h.v;
}

// ---- GEMM (m97-style): C = A @ W^T + bias.  A fp16 [4096x1024], W fp16 [1024x1024] [out][in].
// Tile: M=128, N=64, BK=32. 4 waves; wave computes 64x32 (mh=w&1 M-half, nh=w>>1 N-half).
// MODE 0 (QKV fused, z selects): z<2 -> fp16 [B,H,N,D]; z==2 -> fp16 [B,H,D,N] (V transposed)
// MODE 1 (O): fp32 row-major [4096][1024]
template<int MODE>
__global__ __launch_bounds__(256,4) void gemm_glds(
    const US* __restrict__ A,
    const US* __restrict__ W0, const US* __restrict__ W1, const US* __restrict__ W2,
    const float* __restrict__ b0, const float* __restrict__ b1, const float* __restrict__ b2,
    void* o0, void* o1, void* o2)
{
  __shared__ __align__(16) US sA[128*32];   // no padding: global_load_lds lane-order constraint
  __shared__ __align__(16) US sW[64*32];
  const int z = (MODE==0) ? blockIdx.z : 0;
  const US* W = (z==0)?W0:(z==1)?W1:W2;
  const float* bias = (z==0)?b0:(z==1)?b1:b2;
  void* out = (z==0)?o0:(z==1)?o1:o2;

  const int t = threadIdx.x;
  const int w = t>>6, lane = t&63;
  const int q = lane>>4, c = lane&15;
  const int mh = w&1, nh = w>>1;
  const int gm0 = blockIdx.y*128, gn0 = blockIdx.x*64;
  const int r16 = lane>>2, seg = lane&3;    // staging: 4 lanes/row, 16B each

  f32x4 acc[4][2] = {};
  for (int kb = 0; kb < 1024; kb += 32) {
    #pragma unroll
    for (int p=0;p<2;++p)
      glds16(&A[(size_t)(gm0 + w*32 + p*16 + r16)*1024 + kb + seg*8],
             &sA[(w*32 + p*16)*32]);
    glds16(&W[(size_t)(gn0 + w*16 + r16)*1024 + kb + seg*8],
           &sW[(w*16)*32]);
    __syncthreads();
    h16x8 af[4], wf[2];
    #pragma unroll
    for (int rt=0;rt<4;++rt) af[rt] = *(const h16x8*)&sA[(mh*64+rt*16+c)*32 + q*8];
    #pragma unroll
    for (int ct=0;ct<2;++ct) wf[ct] = *(const h16x8*)&sW[(nh*32+ct*16+c)*32 + q*8];
    #pragma unroll
    for (int rt=0;rt<4;++rt)
      #pragma unroll
      for (int ct=0;ct<2;++ct)
        acc[rt][ct] = MFMA16F(af[rt], wf[ct], acc[rt][ct]);
    __syncthreads();
  }
  #pragma unroll
  for (int rt=0;rt<4;++rt)
  #pragma unroll
  for (int ct=0;ct<2;++ct) {
    int col = gn0 + nh*32 + ct*16 + c;
    float bv = bias[col];
    int rowb = gm0 + mh*64 + rt*16 + q*4;
    if (MODE==0 && z==2) {
      // V transposed: [B,H,D,N]; pack 4 consecutive n per 8B store
      int b = rowb>>11, n = rowb & (N_-1);
      int hh = col>>6, d = col & 63;
      U4 pk;
      #pragma unroll
      for (int r=0;r<4;++r) pk.u[r] = f2h(acc[rt][ct][r] + bv);
      *(uint2*)&((US*)out)[((size_t)(b*H_+hh)*D_ + d)*N_ + n] = pk.v;
    } else {
      #pragma unroll
      for (int r=0;r<4;++r) {
        int row = rowb + r;
        float v = acc[rt][ct][r] + bv;
        if (MODE==1) {
          ((float*)out)[(size_t)row*1024 + col] = v;
        } else {
          int b = row>>11, n = row & (N_-1), hh = col>>6, d = col & 63;
          ((US*)out)[((size_t)(b*H_+hh)*N_+n)*D_ + d] = f2h(v);
        }
      }
    }
  }
}

// ---- Flash attention, fp16, no block-level sync.
// Wave w owns 16 q-rows; K and V^T B-frags loaded straight from global (L2-resident via XCD swizzle).
// 128-key tiles; online softmax with deferred l-reduction; exp2 domain.
#define PSTR 136   // 128 + 8 pad
#define SCL  11.5415603828f   // 8 * log2(e)
__global__ __launch_bounds__(256,4) void attn(
    const US* __restrict__ Qf, const US* __restrict__ Kf, const US* __restrict__ Vt,
    US* __restrict__ Hout)
{
  __shared__ __align__(16) US sP[4][16*PSTR];   // per-wave P transpose buffer
  const int t = threadIdx.x;
  const int w = t>>6, lane = t&63, q = lane>>4, c = lane&15;
  const int id = blockIdx.x;
  // XCD swizzle: all 32 q-blocks of one (b,h) land on one XCD (id%8 stable)
  const int bh = ((id & 7) << 2) | ((id >> 3) & 3);
  const int n0 = (id >> 5) * 64;
  const US* Kp = Kf + (size_t)bh * (N_*D_);
  const US* Vp = Vt + (size_t)bh * (D_*N_);

  // Q A-frags from global: row = n0 + w*16 + c, k-chunks q*8, 32+q*8
  const size_t qoff = (size_t)bh*(N_*D_) + (size_t)(n0 + w*16 + c)*D_;
  h16x8 qa0 = *(const h16x8*)&Qf[qoff + q*8];
  h16x8 qa1 = *(const h16x8*)&Qf[qoff + 32 + q*8];

  float mi[4], ls[4];
  f32x4 o[4];
  #pragma unroll
  for (int r=0;r<4;++r){ mi[r] = -INFINITY; ls[r] = 0.f; f32x4 zz = {}; o[r] = zz; }

  for (int mt=0; mt<16; ++mt) {
    const int m0 = mt*128;
    // S tile: 16 q-rows x 128 keys (scaled into exp2 domain)
    f32x4 s[8];
    #pragma unroll
    for (int j=0;j<8;++j){
      const US* kr = &Kp[(size_t)(m0 + j*16 + c)*D_];
      h16x8 b0v = *(const h16x8*)&kr[q*8];
      h16x8 b1v = *(const h16x8*)&kr[32 + q*8];
      f32x4 sv = {};
      sv = MFMA16F(qa0, b0v, sv);
      sv = MFMA16F(qa1, b1v, sv);
      s[j] = sv * SCL;
    }
    // online softmax: lane-group q holds rows q*4+r; reduce max over 16 lanes
    float alpha[4];
    #pragma unroll
    for (int r=0;r<4;++r){
      float v0 = fmaxf(fmaxf(s[0][r],s[1][r]), fmaxf(s[2][r],s[3][r]));
      float v1 = fmaxf(fmaxf(s[4][r],s[5][r]), fmaxf(s[6][r],s[7][r]));
      float v = fmaxf(v0, v1);
      v = fmaxf(v, __shfl_xor(v,1));
      v = fmaxf(v, __shfl_xor(v,2));
      v = fmaxf(v, __shfl_xor(v,4));
      v = fmaxf(v, __shfl_xor(v,8));
      float mnew = fmaxf(mi[r], v);
      alpha[r] = exp2f(mi[r]-mnew);
      mi[r] = mnew;
      float ps = 0.f;
      #pragma unroll
      for (int j=0;j<8;++j){
        float p = exp2f(s[j][r]-mnew);
        s[j][r] = p;
        ps += p;
      }
      ls[r] = ls[r]*alpha[r] + ps;   // lane-local partial; cross-lane reduce deferred
    }
    #pragma unroll
    for (int dt=0;dt<4;++dt)
      #pragma unroll
      for (int r=0;r<4;++r) o[dt][r] *= alpha[r];
    // P: C-layout regs -> wave-private LDS -> A-layout frags
    #pragma unroll
    for (int j=0;j<8;++j)
      #pragma unroll
      for (int r=0;r<4;++r)
        sP[w][(q*4+r)*PSTR + j*16 + c] = f2h(s[j][r]);
    h16x8 pa[4];
    #pragma unroll
    for (int kc=0;kc<4;++kc)
      pa[kc] = *(const h16x8*)&sP[w][c*PSTR + kc*32 + q*8];
    // PV: B-frags straight from global V^T [d][m]
    #pragma unroll
    for (int dt=0;dt<4;++dt){
      const US* vr = &Vp[(size_t)(dt*16 + c)*N_ + m0];
      #pragma unroll
      for (int kc=0;kc<4;++kc){
        h16x8 vbv = *(const h16x8*)&vr[kc*32 + q*8];
        o[dt] = MFMA16F(pa[kc], vbv, o[dt]);
      }
    }
  }
  // final l reduction over the 16-lane row group
  float li[4];
  #pragma unroll
  for (int r=0;r<4;++r){
    float v = ls[r];
    v += __shfl_xor(v,1);
    v += __shfl_xor(v,2);
    v += __shfl_xor(v,4);
    v += __shfl_xor(v,8);
    li[r] = v;
  }
  const int b = bh>>4, hh = bh&15;
  #pragma unroll
  for (int dt=0;dt<4;++dt){
    #pragma unroll
    for (int r=0;r<4;++r){
      int n = n0 + w*16 + q*4 + r;
      int d = dt*16 + c;
      Hout[((size_t)(b*N_+n)*H_+hh)*D_ + d] = f2h(o[dt][r] / li[r]);  // [B,N,E] fp16
    }
  }
}

extern "C" void kernel_launch(void* const* d_in, const int* in_sizes, int n_in,
                              void* d_out, int out_size, void* d_ws, size_t ws_size,
                              hipStream_t stream)
{
  const float* x  = (const float*)d_in[0];
  const float* Wq = (const float*)d_in[1];
  const float* bq = (const float*)d_in[2];
  const float* Wk = (const float*)d_in[3];
  const float* bk = (const float*)d_in[4];
  const float* Wv = (const float*)d_in[5];
  const float* bv = (const float*)d_in[6];
  const float* Wo = (const float*)d_in[7];
  const float* bo = (const float*)d_in[8];
  US* ws  = (US*)d_ws;
  const size_t M1 = 1048576;
  US* xh  = ws;                 // 4M fp16
  US* Wqf = ws + 4*M1;          // 1M
  US* Wkf = ws + 5*M1;
  US* Wvf = ws + 6*M1;
  US* Wof = ws + 7*M1;
  US* Qf  = ws + 8*M1;          // 4M, [B,H,N,D]
  US* Kf  = ws + 12*M1;         // 4M, [B,H,N,D]
  US* Vtb = ws + 16*M1;         // 4M, [B,H,D,N]
  US* Hf  = ws + 20*M1;         // 4M, [B,N,E]  -> 48 MB total

  conv_x<<<2048, 256, 0, stream>>>(x, xh);
  conv_w<<<dim3(512,4,1), 256, 0, stream>>>(Wq, Wk, Wv, Wo, Wqf, Wkf, Wvf, Wof);

  gemm_glds<0><<<dim3(16,32,3), 256, 0, stream>>>(xh, Wqf, Wkf, Wvf, bq, bk, bv, Qf, Kf, Vtb);
  attn<<<1024, 256, 0, stream>>>(Qf, Kf, Vtb, Hf);
  gemm_glds<1><<<dim3(16,32,1), 256, 0, stream>>>(Hf, Wof, nullptr, nullptr, bo, nullptr, nullptr, d_out, nullptr, nullptr);
}

// Round 6
// 232.893 us; speedup vs baseline: 1.6445x; 1.6445x over previous
//
#include <hip/hip_runtime.h>
#include <math.h>

#define B_ 2
#define N_ 2048
#define E_ 1024
#define H_ 16
#define D_ 64

typedef unsigned short US;
typedef _Float16 h16x8 __attribute__((ext_vector_type(8)));
typedef float f32x4 __attribute__((ext_vector_type(4)));
#define MFMA16F(a,b,c) __builtin_amdgcn_mfma_f32_16x16x32_f16(a,b,c,0,0,0)

union HU { _Float16 h; US u; };
__device__ __forceinline__ US f2h(float f){ HU x; x.h = (_Float16)f; return x.u; }
__device__ __forceinline__ unsigned pkh(float a, float b){
  return (unsigned)f2h(a) | ((unsigned)f2h(b)<<16);
}

union U8 { US u[8]; uint4 v; };
union U4 { US u[4]; uint2 v; };

// async global->LDS, 16B/lane; LDS dest = wave-uniform base + lane*16 (no padding possible)
__device__ __forceinline__ void glds16(const US* g, US* l){
  __builtin_amdgcn_global_load_lds(
    (const __attribute__((address_space(1))) unsigned int*)(const void*)g,
    (__attribute__((address_space(3))) unsigned int*)(void*)l, 16, 0, 0);
}

// ---- converts: fp32 -> fp16 ----
__global__ __launch_bounds__(256) void conv_x(const float* __restrict__ x, US* __restrict__ hi)
{
  int i = (blockIdx.x*256 + threadIdx.x)*8;
  float f[8];
  *(float4*)&f[0] = *(const float4*)&x[i];
  *(float4*)&f[4] = *(const float4*)&x[i+4];
  U8 h;
  #pragma unroll
  for (int j=0;j<8;++j) h.u[j] = f2h(f[j]);
  *(uint4*)&hi[i] = h.v;
}

__global__ __launch_bounds__(256) void conv_w(const float* __restrict__ w0, const float* __restrict__ w1,
                                              const float* __restrict__ w2, const float* __restrict__ w3,
                                              US* __restrict__ d0, US* __restrict__ d1,
                                              US* __restrict__ d2, US* __restrict__ d3)
{
  const float* s; US* d;
  switch (blockIdx.y) {
    case 0: s=w0; d=d0; break;
    case 1: s=w1; d=d1; break;
    case 2: s=w2; d=d2; break;
    default: s=w3; d=d3; break;
  }
  int i = (blockIdx.x*256 + threadIdx.x)*8;
  float f[8];
  *(float4*)&f[0] = *(const float4*)&s[i];
  *(float4*)&f[4] = *(const float4*)&s[i+4];
  U8 h;
  #pragma unroll
  for (int j=0;j<8;++j) h.u[j] = f2h(f[j]);
  *(uint4*)&d[i] = h.v;
}

// ---- GEMM (m97-style 128x128, BK=32): C = A @ W^T + bias.
// A fp16 [4096x1024], W fp16 [1024x1024] [out][in]. 4 waves, each 64x64 (4x4 frags).
// MODE 0 (QKV fused, z): z<2 -> fp16 [B,H,N,D]; z==2 -> fp16 [B,H,D,N] (V transposed)
// MODE 1 (O): fp32 row-major [4096][1024]
template<int MODE>
__global__ __launch_bounds__(256,2) void gemm_glds(
    const US* __restrict__ A,
    const US* __restrict__ W0, const US* __restrict__ W1, const US* __restrict__ W2,
    const float* __restrict__ b0, const float* __restrict__ b1, const float* __restrict__ b2,
    void* o0, void* o1, void* o2)
{
  __shared__ __align__(16) US sA[128*32];   // compact: glds lane-order constraint
  __shared__ __align__(16) US sW[128*32];
  const int z = (MODE==0) ? blockIdx.z : 0;
  const US* W = (z==0)?W0:(z==1)?W1:W2;
  const float* bias = (z==0)?b0:(z==1)?b1:b2;
  void* out = (z==0)?o0:(z==1)?o1:o2;

  const int t = threadIdx.x;
  const int w = t>>6, lane = t&63;
  const int q = lane>>4, c = lane&15;
  const int mq = (w>>1)*64, nq = (w&1)*64;
  const int gm0 = blockIdx.y*128, gn0 = blockIdx.x*128;
  const int r16 = lane>>2, seg = lane&3;    // staging: 4 lanes/row, 16B each

  f32x4 acc[4][4] = {};
  for (int kb = 0; kb < 1024; kb += 32) {
    #pragma unroll
    for (int p=0;p<2;++p){
      int rb = (w*2+p)*16;
      glds16(&A[(size_t)(gm0 + rb + r16)*1024 + kb + seg*8], &sA[rb*32]);
      glds16(&W[(size_t)(gn0 + rb + r16)*1024 + kb + seg*8], &sW[rb*32]);
    }
    __syncthreads();
    h16x8 af[4], wf[4];
    #pragma unroll
    for (int rt=0;rt<4;++rt) af[rt] = *(const h16x8*)&sA[(mq+rt*16+c)*32 + q*8];
    #pragma unroll
    for (int ct=0;ct<4;++ct) wf[ct] = *(const h16x8*)&sW[(nq+ct*16+c)*32 + q*8];
    #pragma unroll
    for (int rt=0;rt<4;++rt)
      #pragma unroll
      for (int ct=0;ct<4;++ct)
        acc[rt][ct] = MFMA16F(af[rt], wf[ct], acc[rt][ct]);
    __syncthreads();
  }
  #pragma unroll
  for (int rt=0;rt<4;++rt)
  #pragma unroll
  for (int ct=0;ct<4;++ct) {
    int col = gn0 + nq + ct*16 + c;
    float bv = bias[col];
    int rowb = gm0 + mq + rt*16 + q*4;
    if (MODE==0 && z==2) {
      int b = rowb>>11, n = rowb & (N_-1);
      int hh = col>>6, d = col & 63;
      U4 pk;
      #pragma unroll
      for (int r=0;r<4;++r) pk.u[r] = f2h(acc[rt][ct][r] + bv);
      *(uint2*)&((US*)out)[((size_t)(b*H_+hh)*D_ + d)*N_ + n] = pk.v;
    } else {
      #pragma unroll
      for (int r=0;r<4;++r) {
        int row = rowb + r;
        float v = acc[rt][ct][r] + bv;
        if (MODE==1) {
          ((float*)out)[(size_t)row*1024 + col] = v;
        } else {
          int b = row>>11, n = row & (N_-1), hh = col>>6, d = col & 63;
          ((US*)out)[((size_t)(b*H_+hh)*N_+n)*D_ + d] = f2h(v);
        }
      }
    }
  }
}

// ---- Flash attention, transposed-S formulation.
// Block = 4 waves = 128 q-rows; wave owns 32 q-rows (2 qsets of 16, as Q B-frags in registers).
// Per 64-key tile: S^T = K·Q^T (A=K from LDS, B=Q regs) -> softmax with keys lane-local ->
// P to per-wave sP (b64 writes) -> O += P·V^T (A=P, B=Vt from LDS).
// CRITICAL (R5 bug): in S^T the q-row is the C-layout COLUMN (c); in O it is the C-layout
// ROW (q*4+r). alpha/l are computed per qrow=g*16+c (replicated across the 4 q-lanes by the
// shfl_xor(16/32) reduction), so rescaling O requires remapping via __shfl(alpha, q*4+r).
#define KSTR 88   // 64+24 pad: ~2-way bank conflicts (free), 16B-aligned rows
#define SCL  11.5415603828f   // 8 * log2(e)
__global__ __launch_bounds__(256,2) void attn(
    const US* __restrict__ Qf, const US* __restrict__ Kf, const US* __restrict__ Vt,
    US* __restrict__ Hout)
{
  __shared__ __align__(16) US sK [64*KSTR];
  __shared__ __align__(16) US sVt[64*KSTR];
  __shared__ __align__(16) US sP [4][32*KSTR];
  const int t = threadIdx.x;
  const int w = t>>6, lane = t&63, q = lane>>4, c = lane&15;
  const int id = blockIdx.x;
  // XCD swizzle: 16 q-tiles of one (b,h) stay on one XCD (id%8 stable across them)
  const int bh = ((id & 7) << 2) | ((id >> 3) & 3);
  const int n0 = (id >> 5) * 128;
  const US* Kp = Kf + (size_t)bh * (N_*D_);
  const US* Vp = Vt + (size_t)bh * (D_*N_);

  // Q B-frags in registers: qset g rows n0 + w*32 + g*16 + c, k-chunks kd*32 + q*8
  h16x8 qb[2][2];
  #pragma unroll
  for (int g=0; g<2; ++g){
    const size_t qoff = (size_t)bh*(N_*D_) + (size_t)(n0 + w*32 + g*16 + c)*D_;
    qb[g][0] = *(const h16x8*)&Qf[qoff + q*8];
    qb[g][1] = *(const h16x8*)&Qf[qoff + 32 + q*8];
  }

  float mi[2] = {-INFINITY, -INFINITY};
  float ls[2] = {0.f, 0.f};
  f32x4 o[2][4] = {};

  const int sr = t>>3, sc8 = (t&7)*8;   // staging: 8 thr/row, 16B each

  for (int mt=0; mt<32; ++mt) {
    const int m0 = mt*64;
    #pragma unroll
    for (int p=0;p<2;++p){
      int r = p*32 + sr;
      *(uint4*)&sK [r*KSTR + sc8] = *(const uint4*)&Kp[(size_t)(m0 + r)*D_ + sc8];
      *(uint4*)&sVt[r*KSTR + sc8] = *(const uint4*)&Vp[(size_t)r*N_ + m0 + sc8];
    }
    __syncthreads();

    // S^T: key f-frags (A=K rows f*16+c), qrow = qset g (B=Q regs)
    f32x4 s[2][4];
    #pragma unroll
    for (int f=0; f<4; ++f){
      h16x8 k0 = *(const h16x8*)&sK[(f*16+c)*KSTR + q*8];
      h16x8 k1 = *(const h16x8*)&sK[(f*16+c)*KSTR + 32 + q*8];
      #pragma unroll
      for (int g=0; g<2; ++g){
        f32x4 sv = {};
        sv = MFMA16F(k0, qb[g][0], sv);
        sv = MFMA16F(k1, qb[g][1], sv);
        s[g][f] = sv * SCL;      // exp2 domain
      }
    }

    // softmax: keys are lane-local (16 per lane: f,r); this lane's qrow = g*16+c
    #pragma unroll
    for (int g=0; g<2; ++g){
      f32x4 vm4 = s[g][0];
      #pragma unroll
      for (int f=1; f<4; ++f){
        vm4[0]=fmaxf(vm4[0],s[g][f][0]); vm4[1]=fmaxf(vm4[1],s[g][f][1]);
        vm4[2]=fmaxf(vm4[2],s[g][f][2]); vm4[3]=fmaxf(vm4[3],s[g][f][3]);
      }
      float v = fmaxf(fmaxf(vm4[0],vm4[1]), fmaxf(vm4[2],vm4[3]));
      v = fmaxf(v, __shfl_xor(v, 16));
      v = fmaxf(v, __shfl_xor(v, 32));     // alpha/mi now replicated across the 4 q-lanes
      float mnew = fmaxf(mi[g], v);
      float alpha = exp2f(mi[g]-mnew);
      mi[g] = mnew;
      float ps = 0.f;
      #pragma unroll
      for (int f=0; f<4; ++f){
        #pragma unroll
        for (int r=0; r<4; ++r){
          float p = exp2f(s[g][f][r]-mnew);
          s[g][f][r] = p;
          ps += p;
        }
      }
      ls[g] = ls[g]*alpha + ps;   // lane-local partial (qrow=g*16+c); reduced at end
      // O rows are qrow = g*16 + q*4 + r -> fetch that row's alpha from lane q*4+r
      float ar[4];
      #pragma unroll
      for (int r=0; r<4; ++r) ar[r] = __shfl(alpha, q*4+r);
      #pragma unroll
      for (int dt=0; dt<4; ++dt){
        o[g][dt][0] *= ar[0]; o[g][dt][1] *= ar[1];
        o[g][dt][2] *= ar[2]; o[g][dt][3] *= ar[3];
      }
      // P store: S^T C-layout (key=f*16+q*4+r, qrow=g*16+c) -> sP[qrow][key], b64 runs over r
      #pragma unroll
      for (int f=0; f<4; ++f){
        uint2 pk;
        pk.x = pkh(s[g][f][0], s[g][f][1]);
        pk.y = pkh(s[g][f][2], s[g][f][3]);
        *(uint2*)&sP[w][(g*16+c)*KSTR + f*16 + q*4] = pk;
      }
    }

    // O += P·V^T : A = P (rows qrow, k=keys), B = Vt (rows d, k=keys)
    #pragma unroll
    for (int g=0; g<2; ++g){
      h16x8 pa0 = *(const h16x8*)&sP[w][(g*16+c)*KSTR + q*8];
      h16x8 pa1 = *(const h16x8*)&sP[w][(g*16+c)*KSTR + 32 + q*8];
      #pragma unroll
      for (int dt=0; dt<4; ++dt){
        h16x8 v0 = *(const h16x8*)&sVt[(dt*16+c)*KSTR + q*8];
        h16x8 v1 = *(const h16x8*)&sVt[(dt*16+c)*KSTR + 32 + q*8];
        o[g][dt] = MFMA16F(pa0, v0, o[g][dt]);
        o[g][dt] = MFMA16F(pa1, v1, o[g][dt]);
      }
    }
    __syncthreads();
  }

  // final l reduction (per qrow=g*16+c), then remap to O rows via shfl
  const int b = bh>>4, hh = bh&15;
  #pragma unroll
  for (int g=0; g<2; ++g){
    float v = ls[g];
    v += __shfl_xor(v, 16);
    v += __shfl_xor(v, 32);
    float inv = 1.0f / v;
    float ir[4];
    #pragma unroll
    for (int r=0; r<4; ++r) ir[r] = __shfl(inv, q*4+r);
    #pragma unroll
    for (int dt=0; dt<4; ++dt){
      #pragma unroll
      for (int r=0; r<4; ++r){
        int n = n0 + w*32 + g*16 + q*4 + r;
        int d = dt*16 + c;
        Hout[((size_t)(b*N_+n)*H_+hh)*D_ + d] = f2h(o[g][dt][r] * ir[r]);  // [B,N,E] fp16
      }
    }
  }
}

extern "C" void kernel_launch(void* const* d_in, const int* in_sizes, int n_in,
                              void* d_out, int out_size, void* d_ws, size_t ws_size,
                              hipStream_t stream)
{
  const float* x  = (const float*)d_in[0];
  const float* Wq = (const float*)d_in[1];
  const float* bq = (const float*)d_in[2];
  const float* Wk = (const float*)d_in[3];
  const float* bk = (const float*)d_in[4];
  const float* Wv = (const float*)d_in[5];
  const float* bv = (const float*)d_in[6];
  const float* Wo = (const float*)d_in[7];
  const float* bo = (const float*)d_in[8];
  US* ws  = (US*)d_ws;
  const size_t M1 = 1048576;
  US* xh  = ws;                 // 4M fp16
  US* Wqf = ws + 4*M1;          // 1M
  US* Wkf = ws + 5*M1;
  US* Wvf = ws + 6*M1;
  US* Wof = ws + 7*M1;
  US* Qf  = ws + 8*M1;          // 4M, [B,H,N,D]
  US* Kf  = ws + 12*M1;         // 4M, [B,H,N,D]
  US* Vtb = ws + 16*M1;         // 4M, [B,H,D,N]
  US* Hf  = ws + 20*M1;         // 4M, [B,N,E]  -> 48 MB total

  conv_x<<<2048, 256, 0, stream>>>(x, xh);
  conv_w<<<dim3(512,4,1), 256, 0, stream>>>(Wq, Wk, Wv, Wo, Wqf, Wkf, Wvf, Wof);

  gemm_glds<0><<<dim3(8,32,3), 256, 0, stream>>>(xh, Wqf, Wkf, Wvf, bq, bk, bv, Qf, Kf, Vtb);
  attn<<<512, 256, 0, stream>>>(Qf, Kf, Vtb, Hf);
  gemm_glds<1><<<dim3(8,32,1), 256, 0, stream>>>(Hf, Wof, nullptr, nullptr, bo, nullptr, nullptr, d_out, nullptr, nullptr);
}

// Round 8
// 231.078 us; speedup vs baseline: 1.6575x; 1.0079x over previous
//
#include <hip/hip_runtime.h>
#include <math.h>

#define B_ 2
#define N_ 2048
#define E_ 1024
#define H_ 16
#define D_ 64

typedef unsigned short US;
typedef _Float16 h16x8 __attribute__((ext_vector_type(8)));
typedef __fp16 fp16x2 __attribute__((ext_vector_type(2)));
typedef float f32x4 __attribute__((ext_vector_type(4)));
#define MFMA16F(a,b,c) __builtin_amdgcn_mfma_f32_16x16x32_f16(a,b,c,0,0,0)
#define SCL  11.5415603828f   // 8 * log2(e), folded into Q at the Q-GEMM epilogue

union HU { _Float16 h; US u; };
__device__ __forceinline__ US f2h(float f){ HU x; x.h = (_Float16)f; return x.u; }
__device__ __forceinline__ unsigned pkrtz(float a, float b){
  union { fp16x2 h; unsigned u; } x;
  x.h = __builtin_amdgcn_cvt_pkrtz(a, b);
  return x.u;
}

union U8 { US u[8]; uint4 v; };
union U4 { US u[4]; uint2 v; };

// async global->LDS, 16B/lane; LDS dest = wave-uniform base + lane*16 (no padding possible)
__device__ __forceinline__ void glds16(const US* g, US* l){
  __builtin_amdgcn_global_load_lds(
    (const __attribute__((address_space(1))) unsigned int*)(const void*)g,
    (__attribute__((address_space(3))) unsigned int*)(void*)l, 16, 0, 0);
}

// ---- converts: fp32 -> fp16 (RNE — these feed Q/K logits, keep unbiased) ----
__global__ __launch_bounds__(256) void conv_x(const float* __restrict__ x, US* __restrict__ hi)
{
  int i = (blockIdx.x*256 + threadIdx.x)*8;
  float f[8];
  *(float4*)&f[0] = *(const float4*)&x[i];
  *(float4*)&f[4] = *(const float4*)&x[i+4];
  U8 h;
  #pragma unroll
  for (int j=0;j<8;++j) h.u[j] = f2h(f[j]);
  *(uint4*)&hi[i] = h.v;
}

__global__ __launch_bounds__(256) void conv_w(const float* __restrict__ w0, const float* __restrict__ w1,
                                              const float* __restrict__ w2, const float* __restrict__ w3,
                                              US* __restrict__ d0, US* __restrict__ d1,
                                              US* __restrict__ d2, US* __restrict__ d3)
{
  const float* s; US* d;
  switch (blockIdx.y) {
    case 0: s=w0; d=d0; break;
    case 1: s=w1; d=d1; break;
    case 2: s=w2; d=d2; break;
    default: s=w3; d=d3; break;
  }
  int i = (blockIdx.x*256 + threadIdx.x)*8;
  float f[8];
  *(float4*)&f[0] = *(const float4*)&s[i];
  *(float4*)&f[4] = *(const float4*)&s[i+4];
  U8 h;
  #pragma unroll
  for (int j=0;j<8;++j) h.u[j] = f2h(f[j]);
  *(uint4*)&d[i] = h.v;
}

// ---- GEMM (glds, 128Mx64N, BK=32): C = A @ W^T + bias.
// A fp16 [4096x1024], W fp16 [1024x1024] [out][in]. 4 waves; wave w owns rows w*32..w*32+31 (2x4 frags).
// MODE 0 (QKV fused, z): z==0 -> Q*SCL fp16 [B,H,N,D]; z==1 -> K fp16 [B,H,N,D];
//                        z==2 -> V fp16 [B,H,D,N] (transposed)
// MODE 1 (O): fp32 row-major [4096][1024]
template<int MODE>
__global__ __launch_bounds__(256,4) void gemm_glds(
    const US* __restrict__ A,
    const US* __restrict__ W0, const US* __restrict__ W1, const US* __restrict__ W2,
    const float* __restrict__ b0, const float* __restrict__ b1, const float* __restrict__ b2,
    void* o0, void* o1, void* o2)
{
  __shared__ __align__(16) US sA[128*32];   // compact: glds lane-order constraint
  __shared__ __align__(16) US sW[64*32];
  const int z = (MODE==0) ? blockIdx.z : 0;
  const US* W = (z==0)?W0:(z==1)?W1:W2;
  const float* bias = (z==0)?b0:(z==1)?b1:b2;
  void* out = (z==0)?o0:(z==1)?o1:o2;

  const int t = threadIdx.x;
  const int w = t>>6, lane = t&63;
  const int q = lane>>4, c = lane&15;
  const int gm0 = blockIdx.y*128, gn0 = blockIdx.x*64;
  const int r16 = lane>>2, seg = lane&3;    // staging: 4 lanes/row, 16B each

  f32x4 acc[2][4] = {};
  for (int kb = 0; kb < 1024; kb += 32) {
    glds16(&A[(size_t)(gm0 + w*32      + r16)*1024 + kb + seg*8], &sA[(w*32)*32]);
    glds16(&A[(size_t)(gm0 + w*32 + 16 + r16)*1024 + kb + seg*8], &sA[(w*32+16)*32]);
    glds16(&W[(size_t)(gn0 + w*16      + r16)*1024 + kb + seg*8], &sW[(w*16)*32]);
    __syncthreads();
    h16x8 af[2], wf[4];
    #pragma unroll
    for (int rt=0;rt<2;++rt) af[rt] = *(const h16x8*)&sA[(w*32+rt*16+c)*32 + q*8];
    #pragma unroll
    for (int ct=0;ct<4;++ct) wf[ct] = *(const h16x8*)&sW[(ct*16+c)*32 + q*8];
    #pragma unroll
    for (int rt=0;rt<2;++rt)
      #pragma unroll
      for (int ct=0;ct<4;++ct)
        acc[rt][ct] = MFMA16F(af[rt], wf[ct], acc[rt][ct]);
    __syncthreads();
  }
  #pragma unroll
  for (int rt=0;rt<2;++rt)
  #pragma unroll
  for (int ct=0;ct<4;++ct) {
    int col = gn0 + ct*16 + c;
    float bv = bias[col];
    int rowb = gm0 + w*32 + rt*16 + q*4;
    if (MODE==0 && z==2) {
      int b = rowb>>11, n = rowb & (N_-1);
      int hh = col>>6, d = col & 63;
      U4 pk;
      #pragma unroll
      for (int r=0;r<4;++r) pk.u[r] = f2h(acc[rt][ct][r] + bv);
      *(uint2*)&((US*)out)[((size_t)(b*H_+hh)*D_ + d)*N_ + n] = pk.v;
    } else {
      #pragma unroll
      for (int r=0;r<4;++r) {
        int row = rowb + r;
        float v = acc[rt][ct][r] + bv;
        if (MODE==1) {
          ((float*)out)[(size_t)row*1024 + col] = v;
        } else {
          if (z==0) v *= SCL;    // fold softmax scale+log2e into Q (fp32, pre-rounding)
          int b = row>>11, n = row & (N_-1), hh = col>>6, d = col & 63;
          ((US*)out)[((size_t)(b*H_+hh)*N_+n)*D_ + d] = f2h(v);
        }
      }
    }
  }
}

// ---- Flash attention, transposed-S formulation, 128-key tiles.
// Block = 4 waves = 128 q-rows; wave owns 32 q-rows (2 qsets of 16, as Q B-frags in registers;
// Q pre-scaled by 8*log2e). Per tile: S^T = K·Q^T -> softmax (keys lane-local, alpha-skip
// branch) -> P packed via v_cvt_pkrtz into per-wave sP (one qset at a time) -> O += P·V^T.
// R5 lesson: S^T's qrow is the C-layout COLUMN (c); O's qrow is the ROW (q*4+r) -> alpha/l
// must be remapped via __shfl(x, q*4+r) before scaling O.
#define KSTR2 72   // K tile row stride (64 d + 8): uniform bank spread for reads/writes
#define VSTR  136  // Vt/P row stride (128 keys + 8)
__global__ __launch_bounds__(256,2) void attn(
    const US* __restrict__ Qf, const US* __restrict__ Kf, const US* __restrict__ Vt,
    US* __restrict__ Hout)
{
  __shared__ __align__(16) US sK [128*KSTR2];
  __shared__ __align__(16) US sVt[64*VSTR];
  __shared__ __align__(16) US sP [4][16*VSTR];   // per-wave, one qset at a time
  const int t = threadIdx.x;
  const int w = t>>6, lane = t&63, q = lane>>4, c = lane&15;
  const int id = blockIdx.x;
  // XCD swizzle: 16 q-tiles of one (b,h) stay on one XCD (id%8 stable across them)
  const int bh = ((id & 7) << 2) | ((id >> 3) & 3);
  const int n0 = (id >> 5) * 128;
  const US* Kp = Kf + (size_t)bh * (N_*D_);
  const US* Vp = Vt + (size_t)bh * (D_*N_);

  // Q B-frags in registers (pre-scaled): qset g rows n0 + w*32 + g*16 + c
  h16x8 qb[2][2];
  #pragma unroll
  for (int g=0; g<2; ++g){
    const size_t qoff = (size_t)bh*(N_*D_) + (size_t)(n0 + w*32 + g*16 + c)*D_;
    qb[g][0] = *(const h16x8*)&Qf[qoff + q*8];
    qb[g][1] = *(const h16x8*)&Qf[qoff + 32 + q*8];
  }

  float mi[2] = {-INFINITY, -INFINITY};
  float ls[2] = {0.f, 0.f};
  f32x4 o[2][4] = {};

  const int kr = t>>3, kc8 = (t&7)*8;     // K staging: 8 thr/row
  const int vr = t>>4, vc8 = (t&15)*8;    // Vt staging: 16 thr/row

  for (int mt=0; mt<16; ++mt) {
    const int m0 = mt*128;
    #pragma unroll
    for (int p=0;p<4;++p){
      int r = p*32 + kr;
      *(uint4*)&sK[r*KSTR2 + kc8] = *(const uint4*)&Kp[(size_t)(m0 + r)*D_ + kc8];
    }
    #pragma unroll
    for (int p=0;p<4;++p){
      int r = p*16 + vr;
      *(uint4*)&sVt[r*VSTR + vc8] = *(const uint4*)&Vp[(size_t)r*N_ + m0 + vc8];
    }
    __syncthreads();

    // S^T: key f-frags (A=K rows f*16+c), qset g (B=Q regs); already in exp2 domain
    f32x4 s[2][8];
    #pragma unroll
    for (int f=0; f<8; ++f){
      h16x8 k0 = *(const h16x8*)&sK[(f*16+c)*KSTR2 + q*8];
      h16x8 k1 = *(const h16x8*)&sK[(f*16+c)*KSTR2 + 32 + q*8];
      #pragma unroll
      for (int g=0; g<2; ++g){
        f32x4 sv = {};
        sv = MFMA16F(k0, qb[g][0], sv);
        sv = MFMA16F(k1, qb[g][1], sv);
        s[g][f] = sv;
      }
    }

    h16x8 pa[2][4];
    #pragma unroll
    for (int g=0; g<2; ++g){
      f32x4 vm = s[g][0];
      #pragma unroll
      for (int f=1; f<8; ++f){
        vm[0]=fmaxf(vm[0],s[g][f][0]); vm[1]=fmaxf(vm[1],s[g][f][1]);
        vm[2]=fmaxf(vm[2],s[g][f][2]); vm[3]=fmaxf(vm[3],s[g][f][3]);
      }
      float v = fmaxf(fmaxf(vm[0],vm[1]), fmaxf(vm[2],vm[3]));
      v = fmaxf(v, __shfl_xor(v, 16));
      v = fmaxf(v, __shfl_xor(v, 32));     // replicated across the 4 q-lanes
      float mnew = fmaxf(mi[g], v);
      // alpha-skip: wave-uniform; max rarely updates after early tiles
      if (!__all(v <= mi[g])) {
        float alpha = exp2f(mi[g]-mnew);
        ls[g] *= alpha;
        float ar[4];
        #pragma unroll
        for (int r=0; r<4; ++r) ar[r] = __shfl(alpha, q*4+r);
        #pragma unroll
        for (int dt=0; dt<4; ++dt){
          o[g][dt][0]*=ar[0]; o[g][dt][1]*=ar[1]; o[g][dt][2]*=ar[2]; o[g][dt][3]*=ar[3];
        }
      }
      mi[g] = mnew;
      float ps = 0.f;
      #pragma unroll
      for (int f=0; f<8; ++f){
        #pragma unroll
        for (int r=0; r<4; ++r){
          float p = exp2f(s[g][f][r]-mnew);
          s[g][f][r] = p;
          ps += p;
        }
      }
      ls[g] += ps;
      // P store: key=f*16+q*4+r, qrow col=c -> sP[c][key], uint2 over r (pkrtz)
      #pragma unroll
      for (int f=0; f<8; ++f){
        uint2 pk;
        pk.x = pkrtz(s[g][f][0], s[g][f][1]);
        pk.y = pkrtz(s[g][f][2], s[g][f][3]);
        *(uint2*)&sP[w][c*VSTR + f*16 + q*4] = pk;
      }
      #pragma unroll
      for (int kc=0; kc<4; ++kc)
        pa[g][kc] = *(const h16x8*)&sP[w][c*VSTR + kc*32 + q*8];
    }

    // O += P·V^T : Vt frags shared across both qsets
    #pragma unroll
    for (int dt=0; dt<4; ++dt){
      h16x8 vf[4];
      #pragma unroll
      for (int kc=0; kc<4; ++kc)
        vf[kc] = *(const h16x8*)&sVt[(dt*16+c)*VSTR + kc*32 + q*8];
      #pragma unroll
      for (int g=0; g<2; ++g)
        #pragma unroll
        for (int kc=0; kc<4; ++kc)
          o[g][dt] = MFMA16F(pa[g][kc], vf[kc], o[g][dt]);
    }
    __syncthreads();
  }

  // final l reduction (per qrow=g*16+c), then remap to O rows via shfl
  const int b = bh>>4, hh = bh&15;
  #pragma unroll
  for (int g=0; g<2; ++g){
    float v = ls[g];
    v += __shfl_xor(v, 16);
    v += __shfl_xor(v, 32);
    float inv = 1.0f / v;
    float ir[4];
    #pragma unroll
    for (int r=0; r<4; ++r) ir[r] = __shfl(inv, q*4+r);
    #pragma unroll
    for (int dt=0; dt<4; ++dt){
      #pragma unroll
      for (int r=0; r<4; ++r){
        int n = n0 + w*32 + g*16 + q*4 + r;
        int d = dt*16 + c;
        Hout[((size_t)(b*N_+n)*H_+hh)*D_ + d] = f2h(o[g][dt][r] * ir[r]);  // [B,N,E] fp16
      }
    }
  }
}

extern "C" void kernel_launch(void* const* d_in, const int* in_sizes, int n_in,
                              void* d_out, int out_size, void* d_ws, size_t ws_size,
                              hipStream_t stream)
{
  const float* x  = (const float*)d_in[0];
  const float* Wq = (const float*)d_in[1];
  const float* bq = (const float*)d_in[2];
  const float* Wk = (const float*)d_in[3];
  const float* bk = (const float*)d_in[4];
  const float* Wv = (const float*)d_in[5];
  const float* bv = (const float*)d_in[6];
  const float* Wo = (const float*)d_in[7];
  const float* bo = (const float*)d_in[8];
  US* ws  = (US*)d_ws;
  const size_t M1 = 1048576;
  US* xh  = ws;                 // 4M fp16
  US* Wqf = ws + 4*M1;          // 1M
  US* Wkf = ws + 5*M1;
  US* Wvf = ws + 6*M1;
  US* Wof = ws + 7*M1;
  US* Qf  = ws + 8*M1;          // 4M, [B,H,N,D], pre-scaled by 8*log2e
  US* Kf  = ws + 12*M1;         // 4M, [B,H,N,D]
  US* Vtb = ws + 16*M1;         // 4M, [B,H,D,N]
  US* Hf  = ws + 20*M1;         // 4M, [B,N,E]  -> 48 MB total

  conv_x<<<2048, 256, 0, stream>>>(x, xh);
  conv_w<<<dim3(512,4,1), 256, 0, stream>>>(Wq, Wk, Wv, Wo, Wqf, Wkf, Wvf, Wof);

  gemm_glds<0><<<dim3(16,32,3), 256, 0, stream>>>(xh, Wqf, Wkf, Wvf, bq, bk, bv, Qf, Kf, Vtb);
  attn<<<512, 256, 0, stream>>>(Qf, Kf, Vtb, Hf);
  gemm_glds<1><<<dim3(16,32,1), 256, 0, stream>>>(Hf, Wof, nullptr, nullptr, bo, nullptr, nullptr, d_out, nullptr, nullptr);
}

// Round 9
// 213.872 us; speedup vs baseline: 1.7908x; 1.0804x over previous
//
#include <hip/hip_runtime.h>
#include <math.h>

#define B_ 2
#define N_ 2048
#define E_ 1024
#define H_ 16
#define D_ 64

typedef unsigned short US;
typedef _Float16 h16x8 __attribute__((ext_vector_type(8)));
typedef __fp16 fp16x2 __attribute__((ext_vector_type(2)));
typedef float f32x4 __attribute__((ext_vector_type(4)));
#define MFMA16F(a,b,c) __builtin_amdgcn_mfma_f32_16x16x32_f16(a,b,c,0,0,0)
#define SCL  11.5415603828f   // 8 * log2(e), folded into Q at the QKV-GEMM epilogue

union HU { _Float16 h; US u; };
__device__ __forceinline__ US f2h(float f){ HU x; x.h = (_Float16)f; return x.u; }
__device__ __forceinline__ unsigned pkrtz(float a, float b){
  union { fp16x2 h; unsigned u; } x;
  x.h = __builtin_amdgcn_cvt_pkrtz(a, b);
  return x.u;
}

union U8 { US u[8]; uint4 v; };
union U4 { US u[4]; uint2 v; };

// async global->LDS, 16B/lane; LDS dest = wave-uniform base + lane*16 (no padding possible)
__device__ __forceinline__ void glds16(const US* g, US* l){
  __builtin_amdgcn_global_load_lds(
    (const __attribute__((address_space(1))) unsigned int*)(const void*)g,
    (__attribute__((address_space(3))) unsigned int*)(void*)l, 16, 0, 0);
}

// ---- fused convert: x (2048 blocks) + Wq/Wk/Wv/Wo (512 blocks each) fp32->fp16 ----
__global__ __launch_bounds__(256) void conv_all(
    const float* __restrict__ x,
    const float* __restrict__ w0, const float* __restrict__ w1,
    const float* __restrict__ w2, const float* __restrict__ w3,
    US* __restrict__ xh, US* __restrict__ Wall)
{
  const int id = blockIdx.x;
  const float* s; US* d; size_t off;
  if (id < 2048) { s = x; d = xh; off = (size_t)id*2048; }
  else {
    int j = id - 2048, wsel = j>>9;
    off = (size_t)(j&511)*2048;
    s = (wsel==0)?w0:(wsel==1)?w1:(wsel==2)?w2:w3;
    d = Wall + (size_t)wsel*1048576;
  }
  size_t i = off + (size_t)threadIdx.x*8;
  float f[8];
  *(float4*)&f[0] = *(const float4*)&s[i];
  *(float4*)&f[4] = *(const float4*)&s[i+4];
  U8 h;
  #pragma unroll
  for (int j=0;j<8;++j) h.u[j] = f2h(f[j]);
  *(uint4*)&d[i] = h.v;
}

// ---- Fused QKV GEMM: {Q,K,V} = x @ W{q,k,v}^T + b.  x-tile staged ONCE per K-step,
// 3 W-tiles share it. Tile 128M x 64N per z, BK=32. Grid 16x32 = 512 = exactly 2 blocks/CU
// at (256,2) -> single occupancy round (R8 lesson: avoid fractional rounds).
// Outputs: Q*SCL fp16 [B,H,N,D]; K fp16 [B,H,N,D]; V fp16 [B,H,D,N] (transposed).
__global__ __launch_bounds__(256,2) void qkv_gemm(
    const US* __restrict__ A, const US* __restrict__ Wall,
    const float* __restrict__ bq, const float* __restrict__ bk, const float* __restrict__ bv,
    US* __restrict__ Qf, US* __restrict__ Kf, US* __restrict__ Vtb)
{
  __shared__ __align__(16) US sA[128*32];
  __shared__ __align__(16) US sW[192*32];   // 3 z-tiles of 64 rows
  const int t = threadIdx.x;
  const int w = t>>6, lane = t&63;
  const int q = lane>>4, c = lane&15;
  const int gm0 = blockIdx.y*128, gn0 = blockIdx.x*64;
  const int r16 = lane>>2, seg = lane&3;    // staging: 4 lanes/row, 16B each

  f32x4 acc[3][2][4] = {};
  for (int kb = 0; kb < 1024; kb += 32) {
    glds16(&A[(size_t)(gm0 + w*32      + r16)*1024 + kb + seg*8], &sA[(w*32)*32]);
    glds16(&A[(size_t)(gm0 + w*32 + 16 + r16)*1024 + kb + seg*8], &sA[(w*32+16)*32]);
    #pragma unroll
    for (int p=0;p<3;++p){
      int cw = w*3 + p;                 // 12 chunks: z = cw>>2, row16 = cw&3
      int z = cw>>2, r0 = (cw&3)*16;
      glds16(&Wall[(size_t)z*1048576 + (size_t)(gn0 + r0 + r16)*1024 + kb + seg*8],
             &sW[(z*64 + r0)*32]);
    }
    __syncthreads();
    h16x8 af0 = *(const h16x8*)&sA[(w*32+c)*32 + q*8];
    h16x8 af1 = *(const h16x8*)&sA[(w*32+16+c)*32 + q*8];
    #pragma unroll
    for (int z=0; z<3; ++z)
      #pragma unroll
      for (int ct=0; ct<4; ++ct){
        h16x8 wf = *(const h16x8*)&sW[(z*64+ct*16+c)*32 + q*8];
        acc[z][0][ct] = MFMA16F(af0, wf, acc[z][0][ct]);
        acc[z][1][ct] = MFMA16F(af1, wf, acc[z][1][ct]);
      }
    __syncthreads();
  }
  #pragma unroll
  for (int z=0; z<3; ++z)
  #pragma unroll
  for (int rt=0; rt<2; ++rt)
  #pragma unroll
  for (int ct=0; ct<4; ++ct) {
    int col = gn0 + ct*16 + c;
    float bv_ = (z==0 ? bq : z==1 ? bk : bv)[col];
    int rowb = gm0 + w*32 + rt*16 + q*4;
    int hh = col>>6, d = col & 63;
    if (z==2) {
      int b = rowb>>11, n = rowb & (N_-1);
      U4 pk;
      #pragma unroll
      for (int r=0;r<4;++r) pk.u[r] = f2h(acc[z][rt][ct][r] + bv_);
      *(uint2*)&Vtb[((size_t)(b*H_+hh)*D_ + d)*N_ + n] = pk.v;
    } else {
      US* dst = (z==0) ? Qf : Kf;
      #pragma unroll
      for (int r=0;r<4;++r) {
        int row = rowb + r;
        float v = acc[z][rt][ct][r] + bv_;
        if (z==0) v *= SCL;      // fold softmax scale + log2e into Q (fp32, pre-rounding)
        int b = row>>11, n = row & (N_-1);
        dst[((size_t)(b*H_+hh)*N_+n)*D_ + d] = f2h(v);
      }
    }
  }
}

// ---- O GEMM: out = H @ Wo^T + bo, fp32 row-major [4096][1024].
// 128M x 64N, BK=32; grid 16x32 = 512 = 2 blocks/CU at (256,4): single round.
__global__ __launch_bounds__(256,4) void o_gemm(
    const US* __restrict__ A, const US* __restrict__ W,
    const float* __restrict__ bias, float* __restrict__ out)
{
  __shared__ __align__(16) US sA[128*32];
  __shared__ __align__(16) US sW[64*32];
  const int t = threadIdx.x;
  const int w = t>>6, lane = t&63;
  const int q = lane>>4, c = lane&15;
  const int gm0 = blockIdx.y*128, gn0 = blockIdx.x*64;
  const int r16 = lane>>2, seg = lane&3;

  f32x4 acc[2][4] = {};
  for (int kb = 0; kb < 1024; kb += 32) {
    glds16(&A[(size_t)(gm0 + w*32      + r16)*1024 + kb + seg*8], &sA[(w*32)*32]);
    glds16(&A[(size_t)(gm0 + w*32 + 16 + r16)*1024 + kb + seg*8], &sA[(w*32+16)*32]);
    glds16(&W[(size_t)(gn0 + w*16      + r16)*1024 + kb + seg*8], &sW[(w*16)*32]);
    __syncthreads();
    h16x8 af0 = *(const h16x8*)&sA[(w*32+c)*32 + q*8];
    h16x8 af1 = *(const h16x8*)&sA[(w*32+16+c)*32 + q*8];
    #pragma unroll
    for (int ct=0; ct<4; ++ct){
      h16x8 wf = *(const h16x8*)&sW[(ct*16+c)*32 + q*8];
      acc[0][ct] = MFMA16F(af0, wf, acc[0][ct]);
      acc[1][ct] = MFMA16F(af1, wf, acc[1][ct]);
    }
    __syncthreads();
  }
  #pragma unroll
  for (int rt=0; rt<2; ++rt)
  #pragma unroll
  for (int ct=0; ct<4; ++ct) {
    int col = gn0 + ct*16 + c;
    float bv_ = bias[col];
    int rowb = gm0 + w*32 + rt*16 + q*4;
    #pragma unroll
    for (int r=0;r<4;++r)
      out[(size_t)(rowb+r)*1024 + col] = acc[rt][ct][r] + bv_;
  }
}

// ---- Flash attention, transposed-S, 128-key tiles, MFMA-computed l (ones-row trick).
// Block = 4 waves = 128 q-rows; wave owns 32 q-rows (2 qsets of 16 as Q B-frags in regs,
// Q pre-scaled by 8*log2e). Per tile: S^T = K·Q^T -> softmax (keys lane-local, alpha-skip)
// -> P pkrtz into per-wave sP -> O += P·V^T with a 5th all-ones B-frag accumulating l.
// l lands in C-layout ROW index (q*4+r) = exactly O's row -> no shfl remap needed.
// R5 lesson retained: alpha (computed per qrow=col c) must be remapped via __shfl(., q*4+r).
#define KSTR2 72   // K tile row stride
#define VSTR  136  // Vt/P row stride (128 keys + 8)
__global__ __launch_bounds__(256,2) void attn(
    const US* __restrict__ Qf, const US* __restrict__ Kf, const US* __restrict__ Vt,
    US* __restrict__ Hout)
{
  __shared__ __align__(16) US sK [128*KSTR2];
  __shared__ __align__(16) US sVt[64*VSTR];
  __shared__ __align__(16) US sP [4][16*VSTR];   // per-wave, one qset at a time
  const int t = threadIdx.x;
  const int w = t>>6, lane = t&63, q = lane>>4, c = lane&15;
  const int id = blockIdx.x;
  // XCD swizzle: 16 q-tiles of one (b,h) stay on one XCD (id%8 stable across them)
  const int bh = ((id & 7) << 2) | ((id >> 3) & 3);
  const int n0 = (id >> 5) * 128;
  const US* Kp = Kf + (size_t)bh * (N_*D_);
  const US* Vp = Vt + (size_t)bh * (D_*N_);

  h16x8 qb[2][2];
  #pragma unroll
  for (int g=0; g<2; ++g){
    const size_t qoff = (size_t)bh*(N_*D_) + (size_t)(n0 + w*32 + g*16 + c)*D_;
    qb[g][0] = *(const h16x8*)&Qf[qoff + q*8];
    qb[g][1] = *(const h16x8*)&Qf[qoff + 32 + q*8];
  }
  h16x8 vones;
  #pragma unroll
  for (int j=0;j<8;++j) vones[j] = (_Float16)1.0f;

  float mi[2] = {-INFINITY, -INFINITY};
  f32x4 o[2][5] = {};        // dt 0..3 = output cols; dt 4 = l accumulator (ones-row)

  const int kr = t>>3, kc8 = (t&7)*8;     // K staging: 8 thr/row
  const int vr = t>>4, vc8 = (t&15)*8;    // Vt staging: 16 thr/row

  for (int mt=0; mt<16; ++mt) {
    const int m0 = mt*128;
    #pragma unroll
    for (int p=0;p<4;++p){
      int r = p*32 + kr;
      *(uint4*)&sK[r*KSTR2 + kc8] = *(const uint4*)&Kp[(size_t)(m0 + r)*D_ + kc8];
    }
    #pragma unroll
    for (int p=0;p<4;++p){
      int r = p*16 + vr;
      *(uint4*)&sVt[r*VSTR + vc8] = *(const uint4*)&Vp[(size_t)r*N_ + m0 + vc8];
    }
    __syncthreads();

    // S^T: key f-frags (A=K rows f*16+c), qset g (B=Q regs); already in exp2 domain
    f32x4 s[2][8];
    #pragma unroll
    for (int f=0; f<8; ++f){
      h16x8 k0 = *(const h16x8*)&sK[(f*16+c)*KSTR2 + q*8];
      h16x8 k1 = *(const h16x8*)&sK[(f*16+c)*KSTR2 + 32 + q*8];
      #pragma unroll
      for (int g=0; g<2; ++g){
        f32x4 sv = {};
        sv = MFMA16F(k0, qb[g][0], sv);
        sv = MFMA16F(k1, qb[g][1], sv);
        s[g][f] = sv;
      }
    }

    h16x8 pa[2][4];
    #pragma unroll
    for (int g=0; g<2; ++g){
      f32x4 vm = s[g][0];
      #pragma unroll
      for (int f=1; f<8; ++f){
        vm[0]=fmaxf(vm[0],s[g][f][0]); vm[1]=fmaxf(vm[1],s[g][f][1]);
        vm[2]=fmaxf(vm[2],s[g][f][2]); vm[3]=fmaxf(vm[3],s[g][f][3]);
      }
      float v = fmaxf(fmaxf(vm[0],vm[1]), fmaxf(vm[2],vm[3]));
      v = fmaxf(v, __shfl_xor(v, 16));
      v = fmaxf(v, __shfl_xor(v, 32));     // replicated across the 4 q-lanes
      float mnew = fmaxf(mi[g], v);
      // alpha-skip: wave-uniform; max rarely updates after early tiles
      if (!__all(v <= mi[g])) {
        float alpha = exp2f(mi[g]-mnew);
        float ar[4];
        #pragma unroll
        for (int r=0; r<4; ++r) ar[r] = __shfl(alpha, q*4+r);
        #pragma unroll
        for (int dt=0; dt<5; ++dt){        // includes the l accumulator
          o[g][dt][0]*=ar[0]; o[g][dt][1]*=ar[1]; o[g][dt][2]*=ar[2]; o[g][dt][3]*=ar[3];
        }
      }
      mi[g] = mnew;
      // exp2 + pack P (rtz); l comes from the ones-row MFMA, not a VALU sum
      #pragma unroll
      for (int f=0; f<8; ++f){
        float p0 = exp2f(s[g][f][0]-mnew);
        float p1 = exp2f(s[g][f][1]-mnew);
        float p2 = exp2f(s[g][f][2]-mnew);
        float p3 = exp2f(s[g][f][3]-mnew);
        uint2 pk;
        pk.x = pkrtz(p0, p1);
        pk.y = pkrtz(p2, p3);
        *(uint2*)&sP[w][c*VSTR + f*16 + q*4] = pk;
      }
      #pragma unroll
      for (int kc=0; kc<4; ++kc)
        pa[g][kc] = *(const h16x8*)&sP[w][c*VSTR + kc*32 + q*8];
    }

    // O += P·V^T : Vt frags shared across both qsets; dt=4 ones-row accumulates l
    #pragma unroll
    for (int dt=0; dt<4; ++dt){
      h16x8 vf[4];
      #pragma unroll
      for (int kc=0; kc<4; ++kc)
        vf[kc] = *(const h16x8*)&sVt[(dt*16+c)*VSTR + kc*32 + q*8];
      #pragma unroll
      for (int g=0; g<2; ++g)
        #pragma unroll
        for (int kc=0; kc<4; ++kc)
          o[g][dt] = MFMA16F(pa[g][kc], vf[kc], o[g][dt]);
    }
    #pragma unroll
    for (int g=0; g<2; ++g)
      #pragma unroll
      for (int kc=0; kc<4; ++kc)
        o[g][4] = MFMA16F(pa[g][kc], vones, o[g][4]);
    __syncthreads();
  }

  // l is already row-indexed (component r = row q*4+r): no shfl needed
  const int b = bh>>4, hh = bh&15;
  #pragma unroll
  for (int g=0; g<2; ++g){
    float ir[4];
    #pragma unroll
    for (int r=0; r<4; ++r) ir[r] = 1.0f / o[g][4][r];
    #pragma unroll
    for (int dt=0; dt<4; ++dt){
      #pragma unroll
      for (int r=0; r<4; ++r){
        int n = n0 + w*32 + g*16 + q*4 + r;
        int d = dt*16 + c;
        Hout[((size_t)(b*N_+n)*H_+hh)*D_ + d] = f2h(o[g][dt][r] * ir[r]);  // [B,N,E] fp16
      }
    }
  }
}

extern "C" void kernel_launch(void* const* d_in, const int* in_sizes, int n_in,
                              void* d_out, int out_size, void* d_ws, size_t ws_size,
                              hipStream_t stream)
{
  const float* x  = (const float*)d_in[0];
  const float* Wq = (const float*)d_in[1];
  const float* bq = (const float*)d_in[2];
  const float* Wk = (const float*)d_in[3];
  const float* bk = (const float*)d_in[4];
  const float* Wv = (const float*)d_in[5];
  const float* bv = (const float*)d_in[6];
  const float* Wo = (const float*)d_in[7];
  const float* bo = (const float*)d_in[8];
  US* ws  = (US*)d_ws;
  const size_t M1 = 1048576;
  US* xh   = ws;                 // 4M fp16
  US* Wall = ws + 4*M1;          // 4M: Wq,Wk,Wv,Wo fp16 contiguous
  US* Qf   = ws + 8*M1;          // 4M, [B,H,N,D], pre-scaled by 8*log2e
  US* Kf   = ws + 12*M1;         // 4M, [B,H,N,D]
  US* Vtb  = ws + 16*M1;         // 4M, [B,H,D,N]
  US* Hf   = ws + 20*M1;         // 4M, [B,N,E]  -> 48 MB total

  conv_all<<<4096, 256, 0, stream>>>(x, Wq, Wk, Wv, Wo, xh, Wall);
  qkv_gemm<<<dim3(16,32), 256, 0, stream>>>(xh, Wall, bq, bk, bv, Qf, Kf, Vtb);
  attn<<<512, 256, 0, stream>>>(Qf, Kf, Vtb, Hf);
  o_gemm<<<dim3(16,32), 256, 0, stream>>>(Hf, Wall + 3*M1, bo, (float*)d_out);
}

// Round 10
// 208.713 us; speedup vs baseline: 1.8351x; 1.0247x over previous
//
#include <hip/hip_runtime.h>
#include <math.h>

#define B_ 2
#define N_ 2048
#define E_ 1024
#define H_ 16
#define D_ 64

typedef unsigned short US;
typedef _Float16 h16x8 __attribute__((ext_vector_type(8)));
typedef __fp16 fp16x2 __attribute__((ext_vector_type(2)));
typedef float f32x4 __attribute__((ext_vector_type(4)));
#define MFMA16F(a,b,c) __builtin_amdgcn_mfma_f32_16x16x32_f16(a,b,c,0,0,0)
#define SCL  11.5415603828f   // 8 * log2(e), folded into Q at the QKV-GEMM epilogue

union HU { _Float16 h; US u; };
__device__ __forceinline__ US f2h(float f){ HU x; x.h = (_Float16)f; return x.u; }
__device__ __forceinline__ unsigned pkrtz(float a, float b){
  union { fp16x2 h; unsigned u; } x;
  x.h = __builtin_amdgcn_cvt_pkrtz(a, b);
  return x.u;
}

union U8 { US u[8]; uint4 v; };
union U4 { US u[4]; uint2 v; };

// async global->LDS, 16B/lane; LDS dest = wave-uniform base + lane*16 (no padding possible)
__device__ __forceinline__ void glds16(const US* g, US* l){
  __builtin_amdgcn_global_load_lds(
    (const __attribute__((address_space(1))) unsigned int*)(const void*)g,
    (__attribute__((address_space(3))) unsigned int*)(void*)l, 16, 0, 0);
}

// ---- fused convert: x (2048 blocks) + Wq/Wk/Wv/Wo (512 blocks each) fp32->fp16 ----
__global__ __launch_bounds__(256) void conv_all(
    const float* __restrict__ x,
    const float* __restrict__ w0, const float* __restrict__ w1,
    const float* __restrict__ w2, const float* __restrict__ w3,
    US* __restrict__ xh, US* __restrict__ Wall)
{
  const int id = blockIdx.x;
  const float* s; US* d; size_t off;
  if (id < 2048) { s = x; d = xh; off = (size_t)id*2048; }
  else {
    int j = id - 2048, wsel = j>>9;
    off = (size_t)(j&511)*2048;
    s = (wsel==0)?w0:(wsel==1)?w1:(wsel==2)?w2:w3;
    d = Wall + (size_t)wsel*1048576;
  }
  size_t i = off + (size_t)threadIdx.x*8;
  float f[8];
  *(float4*)&f[0] = *(const float4*)&s[i];
  *(float4*)&f[4] = *(const float4*)&s[i+4];
  U8 h;
  #pragma unroll
  for (int j=0;j<8;++j) h.u[j] = f2h(f[j]);
  *(uint4*)&d[i] = h.v;
}

// ---- QKV GEMM, m97 geometry: 128x128 tile, BK=32, z-sliced (z selects Wq/Wk/Wv).
// Grid (8,32,3) = 768 blocks = exactly 3 blocks/CU at (256,3) -> single occupancy round.
// 4 waves, each 64x64 (4x4 frags); R/M = 16 MFMA : 8 ds_read_b128 = m97's proven ratio.
// Outputs: z=0 Q*SCL fp16 [B,H,N,D]; z=1 K fp16 [B,H,N,D]; z=2 V fp16 [B,H,D,N] (transposed).
__global__ __launch_bounds__(256,3) void qkv_gemm(
    const US* __restrict__ A, const US* __restrict__ Wall,
    const float* __restrict__ bq, const float* __restrict__ bk, const float* __restrict__ bv,
    US* __restrict__ Qf, US* __restrict__ Kf, US* __restrict__ Vtb)
{
  __shared__ __align__(16) US sA[128*32];
  __shared__ __align__(16) US sW[128*32];
  const int z = blockIdx.z;
  const US* W = Wall + (size_t)z*1048576;
  const float* bias = (z==0)?bq:(z==1)?bk:bv;

  const int t = threadIdx.x;
  const int w = t>>6, lane = t&63;
  const int q = lane>>4, c = lane&15;
  const int mq = (w>>1)*64, nq = (w&1)*64;
  const int gm0 = blockIdx.y*128, gn0 = blockIdx.x*128;
  const int r16 = lane>>2, seg = lane&3;    // staging: 4 lanes/row, 16B each

  f32x4 acc[4][4] = {};
  for (int kb = 0; kb < 1024; kb += 32) {
    #pragma unroll
    for (int p=0;p<2;++p){
      int rb = (w*2+p)*16;
      glds16(&A[(size_t)(gm0 + rb + r16)*1024 + kb + seg*8], &sA[rb*32]);
      glds16(&W[(size_t)(gn0 + rb + r16)*1024 + kb + seg*8], &sW[rb*32]);
    }
    __syncthreads();
    h16x8 af[4], wf[4];
    #pragma unroll
    for (int rt=0;rt<4;++rt) af[rt] = *(const h16x8*)&sA[(mq+rt*16+c)*32 + q*8];
    #pragma unroll
    for (int ct=0;ct<4;++ct) wf[ct] = *(const h16x8*)&sW[(nq+ct*16+c)*32 + q*8];
    #pragma unroll
    for (int rt=0;rt<4;++rt)
      #pragma unroll
      for (int ct=0;ct<4;++ct)
        acc[rt][ct] = MFMA16F(af[rt], wf[ct], acc[rt][ct]);
    __syncthreads();
  }
  #pragma unroll
  for (int rt=0;rt<4;++rt)
  #pragma unroll
  for (int ct=0;ct<4;++ct) {
    int col = gn0 + nq + ct*16 + c;
    float bv_ = bias[col];
    int rowb = gm0 + mq + rt*16 + q*4;
    int hh = col>>6, d = col & 63;
    if (z==2) {
      int b = rowb>>11, n = rowb & (N_-1);
      U4 pk;
      #pragma unroll
      for (int r=0;r<4;++r) pk.u[r] = f2h(acc[rt][ct][r] + bv_);
      *(uint2*)&Vtb[((size_t)(b*H_+hh)*D_ + d)*N_ + n] = pk.v;
    } else {
      US* dst = (z==0) ? Qf : Kf;
      #pragma unroll
      for (int r=0;r<4;++r) {
        int row = rowb + r;
        float v = acc[rt][ct][r] + bv_;
        if (z==0) v *= SCL;      // fold softmax scale + log2e into Q (fp32, pre-rounding)
        int b = row>>11, n = row & (N_-1);
        dst[((size_t)(b*H_+hh)*N_+n)*D_ + d] = f2h(v);
      }
    }
  }
}

// ---- O GEMM: out = H @ Wo^T + bo, fp32 row-major [4096][1024].
// 128M x 64N, BK=32; grid 16x32 = 512 = 2 blocks/CU at (256,4): single round.
__global__ __launch_bounds__(256,4) void o_gemm(
    const US* __restrict__ A, const US* __restrict__ W,
    const float* __restrict__ bias, float* __restrict__ out)
{
  __shared__ __align__(16) US sA[128*32];
  __shared__ __align__(16) US sW[64*32];
  const int t = threadIdx.x;
  const int w = t>>6, lane = t&63;
  const int q = lane>>4, c = lane&15;
  const int gm0 = blockIdx.y*128, gn0 = blockIdx.x*64;
  const int r16 = lane>>2, seg = lane&3;

  f32x4 acc[2][4] = {};
  for (int kb = 0; kb < 1024; kb += 32) {
    glds16(&A[(size_t)(gm0 + w*32      + r16)*1024 + kb + seg*8], &sA[(w*32)*32]);
    glds16(&A[(size_t)(gm0 + w*32 + 16 + r16)*1024 + kb + seg*8], &sA[(w*32+16)*32]);
    glds16(&W[(size_t)(gn0 + w*16      + r16)*1024 + kb + seg*8], &sW[(w*16)*32]);
    __syncthreads();
    h16x8 af0 = *(const h16x8*)&sA[(w*32+c)*32 + q*8];
    h16x8 af1 = *(const h16x8*)&sA[(w*32+16+c)*32 + q*8];
    #pragma unroll
    for (int ct=0; ct<4; ++ct){
      h16x8 wf = *(const h16x8*)&sW[(ct*16+c)*32 + q*8];
      acc[0][ct] = MFMA16F(af0, wf, acc[0][ct]);
      acc[1][ct] = MFMA16F(af1, wf, acc[1][ct]);
    }
    __syncthreads();
  }
  #pragma unroll
  for (int rt=0; rt<2; ++rt)
  #pragma unroll
  for (int ct=0; ct<4; ++ct) {
    int col = gn0 + ct*16 + c;
    float bv_ = bias[col];
    int rowb = gm0 + w*32 + rt*16 + q*4;
    #pragma unroll
    for (int r=0;r<4;++r)
      out[(size_t)(rowb+r)*1024 + col] = acc[rt][ct][r] + bv_;
  }
}

// ---- Flash attention: 512-thread blocks (8 waves), transposed-S, 128-key tiles.
// Wave w owns 16 q-rows (one qset as Q B-frags in regs, Q pre-scaled by 8*log2e).
// Grid 512 blocks x 8 waves = 16 waves/CU (2 blocks at 70.7 KB LDS) -> 2x R9 occupancy
// to hide the exp2/pkrtz dependent chains. Ones-row MFMA accumulates l (row-indexed,
// no shfl remap). R5 lesson: alpha (per qrow=col c) remapped via __shfl(., q*4+r).
#define KSTR2 72   // K tile row stride
#define VSTR  136  // Vt/P row stride (128 keys + 8)
__global__ __launch_bounds__(512,4) void attn(
    const US* __restrict__ Qf, const US* __restrict__ Kf, const US* __restrict__ Vt,
    US* __restrict__ Hout)
{
  __shared__ __align__(16) US sK [128*KSTR2];
  __shared__ __align__(16) US sVt[64*VSTR];
  __shared__ __align__(16) US sP [8][16*VSTR];   // per-wave P buffer (16 q-rows)
  const int t = threadIdx.x;
  const int w = t>>6, lane = t&63, q = lane>>4, c = lane&15;
  const int id = blockIdx.x;
  // XCD swizzle: 16 q-tiles of one (b,h) stay on one XCD (id%8 stable across them)
  const int bh = ((id & 7) << 2) | ((id >> 3) & 3);
  const int n0 = (id >> 5) * 128;
  const US* Kp = Kf + (size_t)bh * (N_*D_);
  const US* Vp = Vt + (size_t)bh * (D_*N_);

  // Q B-frags in registers (pre-scaled): rows n0 + w*16 + c
  const size_t qoff = (size_t)bh*(N_*D_) + (size_t)(n0 + w*16 + c)*D_;
  h16x8 qb0 = *(const h16x8*)&Qf[qoff + q*8];
  h16x8 qb1 = *(const h16x8*)&Qf[qoff + 32 + q*8];
  h16x8 vones;
  #pragma unroll
  for (int j=0;j<8;++j) vones[j] = (_Float16)1.0f;

  float mi = -INFINITY;
  f32x4 o[5] = {};           // 0..3 = output d-cols; 4 = l accumulator (ones-row)

  const int kr = t>>3, kc8 = (t&7)*8;     // K staging: 8 thr/row, 64 rows/pass
  const int vr = t>>4, vc8 = (t&15)*8;    // Vt staging: 16 thr/row, 32 rows/pass

  for (int mt=0; mt<16; ++mt) {
    const int m0 = mt*128;
    #pragma unroll
    for (int p=0;p<2;++p){
      int r = p*64 + kr;
      *(uint4*)&sK[r*KSTR2 + kc8] = *(const uint4*)&Kp[(size_t)(m0 + r)*D_ + kc8];
    }
    #pragma unroll
    for (int p=0;p<2;++p){
      int r = p*32 + vr;
      *(uint4*)&sVt[r*VSTR + vc8] = *(const uint4*)&Vp[(size_t)r*N_ + m0 + vc8];
    }
    __syncthreads();

    // S^T: key f-frags (A=K rows f*16+c), qrow = B-col; already in exp2 domain
    f32x4 s[8];
    #pragma unroll
    for (int f=0; f<8; ++f){
      h16x8 k0 = *(const h16x8*)&sK[(f*16+c)*KSTR2 + q*8];
      h16x8 k1 = *(const h16x8*)&sK[(f*16+c)*KSTR2 + 32 + q*8];
      f32x4 sv = {};
      sv = MFMA16F(k0, qb0, sv);
      sv = MFMA16F(k1, qb1, sv);
      s[f] = sv;
    }

    // softmax: keys lane-local (32/lane); this lane's qrow = c
    f32x4 vm = s[0];
    #pragma unroll
    for (int f=1; f<8; ++f){
      vm[0]=fmaxf(vm[0],s[f][0]); vm[1]=fmaxf(vm[1],s[f][1]);
      vm[2]=fmaxf(vm[2],s[f][2]); vm[3]=fmaxf(vm[3],s[f][3]);
    }
    float v = fmaxf(fmaxf(vm[0],vm[1]), fmaxf(vm[2],vm[3]));
    v = fmaxf(v, __shfl_xor(v, 16));
    v = fmaxf(v, __shfl_xor(v, 32));     // replicated across the 4 q-lanes
    float mnew = fmaxf(mi, v);
    // alpha-skip: wave-uniform; max rarely updates after early tiles
    if (!__all(v <= mi)) {
      float alpha = exp2f(mi-mnew);
      float ar[4];
      #pragma unroll
      for (int r=0; r<4; ++r) ar[r] = __shfl(alpha, q*4+r);
      #pragma unroll
      for (int dt=0; dt<5; ++dt){        // includes the l accumulator
        o[dt][0]*=ar[0]; o[dt][1]*=ar[1]; o[dt][2]*=ar[2]; o[dt][3]*=ar[3];
      }
    }
    mi = mnew;
    // exp2 + pack P (rtz); l comes from the ones-row MFMA
    #pragma unroll
    for (int f=0; f<8; ++f){
      float p0 = exp2f(s[f][0]-mnew);
      float p1 = exp2f(s[f][1]-mnew);
      float p2 = exp2f(s[f][2]-mnew);
      float p3 = exp2f(s[f][3]-mnew);
      uint2 pk;
      pk.x = pkrtz(p0, p1);
      pk.y = pkrtz(p2, p3);
      *(uint2*)&sP[w][c*VSTR + f*16 + q*4] = pk;
    }
    h16x8 pa[4];
    #pragma unroll
    for (int kc=0; kc<4; ++kc)
      pa[kc] = *(const h16x8*)&sP[w][c*VSTR + kc*32 + q*8];

    // O += P·V^T
    #pragma unroll
    for (int dt=0; dt<4; ++dt){
      #pragma unroll
      for (int kc=0; kc<4; ++kc){
        h16x8 vf = *(const h16x8*)&sVt[(dt*16+c)*VSTR + kc*32 + q*8];
        o[dt] = MFMA16F(pa[kc], vf, o[dt]);
      }
    }
    #pragma unroll
    for (int kc=0; kc<4; ++kc)
      o[4] = MFMA16F(pa[kc], vones, o[4]);
    __syncthreads();
  }

  // l is row-indexed (component r = row q*4+r): no shfl needed
  const int b = bh>>4, hh = bh&15;
  float ir[4];
  #pragma unroll
  for (int r=0; r<4; ++r) ir[r] = 1.0f / o[4][r];
  #pragma unroll
  for (int dt=0; dt<4; ++dt){
    #pragma unroll
    for (int r=0; r<4; ++r){
      int n = n0 + w*16 + q*4 + r;
      int d = dt*16 + c;
      Hout[((size_t)(b*N_+n)*H_+hh)*D_ + d] = f2h(o[dt][r] * ir[r]);  // [B,N,E] fp16
    }
  }
}

extern "C" void kernel_launch(void* const* d_in, const int* in_sizes, int n_in,
                              void* d_out, int out_size, void* d_ws, size_t ws_size,
                              hipStream_t stream)
{
  const float* x  = (const float*)d_in[0];
  const float* Wq = (const float*)d_in[1];
  const float* bq = (const float*)d_in[2];
  const float* Wk = (const float*)d_in[3];
  const float* bk = (const float*)d_in[4];
  const float* Wv = (const float*)d_in[5];
  const float* bv = (const float*)d_in[6];
  const float* Wo = (const float*)d_in[7];
  const float* bo = (const float*)d_in[8];
  US* ws  = (US*)d_ws;
  const size_t M1 = 1048576;
  US* xh   = ws;                 // 4M fp16
  US* Wall = ws + 4*M1;          // 4M: Wq,Wk,Wv,Wo fp16 contiguous
  US* Qf   = ws + 8*M1;          // 4M, [B,H,N,D], pre-scaled by 8*log2e
  US* Kf   = ws + 12*M1;         // 4M, [B,H,N,D]
  US* Vtb  = ws + 16*M1;         // 4M, [B,H,D,N]
  US* Hf   = ws + 20*M1;         // 4M, [B,N,E]  -> 48 MB total

  conv_all<<<4096, 256, 0, stream>>>(x, Wq, Wk, Wv, Wo, xh, Wall);
  qkv_gemm<<<dim3(8,32,3), 256, 0, stream>>>(xh, Wall, bq, bk, bv, Qf, Kf, Vtb);
  attn<<<512, 512, 0, stream>>>(Qf, Kf, Vtb, Hf);
  o_gemm<<<dim3(16,32), 256, 0, stream>>>(Hf, Wall + 3*M1, bo, (float*)d_out);
}